// Round 5
// baseline (881.504 us; speedup 1.0000x reference)
//
#include <hip/hip_runtime.h>

#define H  64
#define TT 512
#define BB 512

typedef _Float16 half8 __attribute__((ext_vector_type(8)));
typedef float    f32x4 __attribute__((ext_vector_type(4)));

__device__ __forceinline__ float frcp(float x) { return __builtin_amdgcn_rcpf(x); }
__device__ __forceinline__ float sigm(float x) { return frcp(1.f + __expf(-x)); }
__device__ __forceinline__ float tanh_fast(float x) { return 1.f - 2.f * frcp(__expf(2.f * x) + 1.f); }

// Barrier that only drains LDS ops: keeps global prefetch loads in flight
// (plain __syncthreads() emits s_waitcnt vmcnt(0) -> kills the prefetch).
__device__ __forceinline__ void bar_lds() {
    asm volatile("s_waitcnt lgkmcnt(0)\n\ts_barrier" ::: "memory");
}

// ---------------------------------------------------------------------------
// xpad: [B*T][32] fp16, cols 0..3 = x (fp32->fp16), cols 4..31 = 0.
// ---------------------------------------------------------------------------
__global__ __launch_bounds__(256) void xpad_prep(const float* __restrict__ x,
                                                 _Float16* __restrict__ xpad) {
    int gid = blockIdx.x * 256 + threadIdx.x;
    int row = gid >> 2, q = gid & 3;
    half8 v = {0,0,0,0,0,0,0,0};
    if (q == 0) {
        float4 xv = ((const float4*)x)[row];
        v[0] = (_Float16)xv.x; v[1] = (_Float16)xv.y;
        v[2] = (_Float16)xv.z; v[3] = (_Float16)xv.w;
    }
    *(half8*)(xpad + (size_t)row * 32 + q * 8) = v;
}

// ---------------------------------------------------------------------------
// MFMA LSTM layer 0. Block = 256 thr = 4 waves, 16 chains (same dir).
// x-MFMA first (regs ready), h-MFMAs last (overlap ds_read latency).
// Depth-2 x prefetch; raw lgkm-only barrier per step.
// ---------------------------------------------------------------------------
__global__ __launch_bounds__(256) void lstm_l0(
    const _Float16* __restrict__ xpad,
    const float* __restrict__ WihF, const float* __restrict__ WhhF, const float* __restrict__ bF,
    const float* __restrict__ WihB, const float* __restrict__ WhhB, const float* __restrict__ bB,
    _Float16* __restrict__ out0)
{
    const int dir = blockIdx.x & 1;
    const int b0  = (blockIdx.x >> 1) * 16;
    const int tid = threadIdx.x;
    const int w = tid >> 6, l = tid & 63, m = l & 15, q = l >> 4;

    const float* Wih = dir ? WihB : WihF;
    const float* Whh = dir ? WhhB : WhhF;
    const float* bia = dir ? bB   : bF;

    half8 Bh[4][2], Bx[4];
    float bv[4];
#pragma unroll
    for (int g = 0; g < 4; ++g) {
        const int n = g * 64 + w * 16 + m;
        bv[g] = bia[n];
#pragma unroll
        for (int s = 0; s < 2; ++s) {
            const float* src = Whh + n * 64 + s * 32 + q * 8;
            half8 tmp;
#pragma unroll
            for (int j = 0; j < 8; ++j) tmp[j] = (_Float16)src[j];
            Bh[g][s] = tmp;
        }
        half8 tx;
#pragma unroll
        for (int j = 0; j < 8; ++j) {
            int k = q * 8 + j;
            tx[j] = (k < 4) ? (_Float16)Wih[n * 4 + k] : (_Float16)0.f;
        }
        Bx[g] = tx;
    }

    __shared__ _Float16 hbuf[2][1024];
    ((unsigned long long*)hbuf)[tid] = 0ULL;
    __syncthreads();

    float c[4] = {0.f, 0.f, 0.f, 0.f};
    const int dt = dir ? -1 : 1;
    int t = dir ? TT - 1 : 0;
    const _Float16* xrow = xpad + (size_t)(b0 + m) * TT * 32 + q * 8;
    half8 ax  = *(const half8*)(xrow + t * 32);
    int t1 = t + dt; if (t1 < 0 || t1 >= TT) t1 = t;
    half8 axn = *(const half8*)(xrow + t1 * 32);
    int p = 0;
    const int swz = (m & 7) * 16;

    for (int s = 0; s < TT; ++s) {
        const char* hb = (const char*)hbuf[p];
        half8 ah0 = *(const half8*)(hb + m * 128 + ((     q * 16 + swz) & 127));
        half8 ah1 = *(const half8*)(hb + m * 128 + ((64 + q * 16 + swz) & 127));
        int t2 = t + 2 * dt; if (t2 < 0 || t2 >= TT) t2 = t;
        half8 axn2 = *(const half8*)(xrow + t2 * 32);

        f32x4 acc[4];
#pragma unroll
        for (int g = 0; g < 4; ++g) {
            f32x4 a = {bv[g], bv[g], bv[g], bv[g]};
            a = __builtin_amdgcn_mfma_f32_16x16x32_f16(ax,  Bx[g],    a, 0, 0, 0);
            a = __builtin_amdgcn_mfma_f32_16x16x32_f16(ah0, Bh[g][0], a, 0, 0, 0);
            acc[g] = __builtin_amdgcn_mfma_f32_16x16x32_f16(ah1, Bh[g][1], a, 0, 0, 0);
        }

        char* hbn = (char*)hbuf[p ^ 1];
#pragma unroll
        for (int i = 0; i < 4; ++i) {
            float e_i = sigm(acc[0][i]), e_f = sigm(acc[1][i]);
            float e_g = tanh_fast(acc[2][i]), e_o = sigm(acc[3][i]);
            c[i] = e_f * c[i] + e_i * e_g;
            float hh = e_o * tanh_fast(c[i]);
            const int ch = q * 4 + i;
            out0[((size_t)(b0 + ch) * TT + t) * 128 + dir * 64 + w * 16 + m] = (_Float16)hh;
            *(_Float16*)(hbn + ch * 128 + (((w * 16 + m) * 2 + (ch & 7) * 16) & 127)) = (_Float16)hh;
        }
        bar_lds();
        p ^= 1; t += dt; ax = axn; axn = axn2;
    }
}

// ---------------------------------------------------------------------------
// MFMA LSTM layer 1: K = 128 (x) + 64 (h). Same pipelining scheme.
// ---------------------------------------------------------------------------
__global__ __launch_bounds__(256) void lstm_l1(
    const _Float16* __restrict__ out0,
    const float* __restrict__ WihF, const float* __restrict__ WhhF, const float* __restrict__ bF,
    const float* __restrict__ WihB, const float* __restrict__ WhhB, const float* __restrict__ bB,
    float* __restrict__ pooled)
{
    const int dir = blockIdx.x & 1;
    const int b0  = (blockIdx.x >> 1) * 16;
    const int tid = threadIdx.x;
    const int w = tid >> 6, l = tid & 63, m = l & 15, q = l >> 4;

    const float* Wih = dir ? WihB : WihF;
    const float* Whh = dir ? WhhB : WhhF;
    const float* bia = dir ? bB   : bF;

    half8 Bf[4][6];
    float bv[4];
#pragma unroll
    for (int g = 0; g < 4; ++g) {
        const int n = g * 64 + w * 16 + m;
        bv[g] = bia[n];
#pragma unroll
        for (int s = 0; s < 6; ++s) {
            const float* src = (s < 2) ? (Whh + n * 64 + s * 32 + q * 8)
                                       : (Wih + n * 128 + (s - 2) * 32 + q * 8);
            half8 tmp;
#pragma unroll
            for (int j = 0; j < 8; ++j) tmp[j] = (_Float16)src[j];
            Bf[g][s] = tmp;
        }
    }

    __shared__ _Float16 hbuf[2][1024];
    ((unsigned long long*)hbuf)[tid] = 0ULL;
    __syncthreads();

    float c[4]  = {0.f, 0.f, 0.f, 0.f};
    float hs[4] = {0.f, 0.f, 0.f, 0.f};
    const int dt = dir ? -1 : 1;
    int t = dir ? TT - 1 : 0;
    const _Float16* xrow = out0 + (size_t)(b0 + m) * TT * 128 + q * 8;

    half8 ax[4], axn[4];
#pragma unroll
    for (int s4 = 0; s4 < 4; ++s4) ax[s4] = *(const half8*)(xrow + t * 128 + s4 * 32);
    int t1 = t + dt; if (t1 < 0 || t1 >= TT) t1 = t;
#pragma unroll
    for (int s4 = 0; s4 < 4; ++s4) axn[s4] = *(const half8*)(xrow + t1 * 128 + s4 * 32);
    int p = 0;
    const int swz = (m & 7) * 16;

    for (int s = 0; s < TT; ++s) {
        const char* hb = (const char*)hbuf[p];
        half8 ah0 = *(const half8*)(hb + m * 128 + ((     q * 16 + swz) & 127));
        half8 ah1 = *(const half8*)(hb + m * 128 + ((64 + q * 16 + swz) & 127));
        int t2 = t + 2 * dt; if (t2 < 0 || t2 >= TT) t2 = t;
        half8 axn2[4];
#pragma unroll
        for (int s4 = 0; s4 < 4; ++s4) axn2[s4] = *(const half8*)(xrow + t2 * 128 + s4 * 32);

        f32x4 acc[4];
#pragma unroll
        for (int g = 0; g < 4; ++g) {
            f32x4 a = {bv[g], bv[g], bv[g], bv[g]};
            a = __builtin_amdgcn_mfma_f32_16x16x32_f16(ax[0], Bf[g][2], a, 0, 0, 0);
            a = __builtin_amdgcn_mfma_f32_16x16x32_f16(ax[1], Bf[g][3], a, 0, 0, 0);
            a = __builtin_amdgcn_mfma_f32_16x16x32_f16(ax[2], Bf[g][4], a, 0, 0, 0);
            a = __builtin_amdgcn_mfma_f32_16x16x32_f16(ax[3], Bf[g][5], a, 0, 0, 0);
            a = __builtin_amdgcn_mfma_f32_16x16x32_f16(ah0,   Bf[g][0], a, 0, 0, 0);
            acc[g] = __builtin_amdgcn_mfma_f32_16x16x32_f16(ah1, Bf[g][1], a, 0, 0, 0);
        }

        char* hbn = (char*)hbuf[p ^ 1];
#pragma unroll
        for (int i = 0; i < 4; ++i) {
            float e_i = sigm(acc[0][i]), e_f = sigm(acc[1][i]);
            float e_g = tanh_fast(acc[2][i]), e_o = sigm(acc[3][i]);
            c[i] = e_f * c[i] + e_i * e_g;
            float hh = e_o * tanh_fast(c[i]);
            hs[i] += hh;
            const int ch = q * 4 + i;
            *(_Float16*)(hbn + ch * 128 + (((w * 16 + m) * 2 + (ch & 7) * 16) & 127)) = (_Float16)hh;
        }
        bar_lds();
        p ^= 1; t += dt;
#pragma unroll
        for (int s4 = 0; s4 < 4; ++s4) { ax[s4] = axn[s4]; axn[s4] = axn2[s4]; }
    }

#pragma unroll
    for (int i = 0; i < 4; ++i)
        pooled[(size_t)(b0 + q * 4 + i) * 128 + dir * 64 + w * 16 + m] = hs[i];
}

// ---------------------------------------------------------------------------
// Head: out[b] = dot(pooled[b], fcw) / T + fcb
// ---------------------------------------------------------------------------
__global__ __launch_bounds__(64) void fc_head(
    const float* __restrict__ pooled,
    const float* __restrict__ fcw, const float* __restrict__ fcb,
    float* __restrict__ out)
{
    const int b = blockIdx.x;
    const int l = threadIdx.x;
    float v = pooled[b * 128 + l] * fcw[l] + pooled[b * 128 + 64 + l] * fcw[64 + l];
#pragma unroll
    for (int o = 32; o > 0; o >>= 1) v += __shfl_down(v, o);
    if (l == 0) out[b] = v * (1.f / (float)TT) + fcb[0];
}

extern "C" void kernel_launch(void* const* d_in, const int* in_sizes, int n_in,
                              void* d_out, int out_size, void* d_ws, size_t ws_size,
                              hipStream_t stream) {
    const float* x       = (const float*)d_in[0];
    const float* Wih_l0f = (const float*)d_in[1];
    const float* Whh_l0f = (const float*)d_in[2];
    const float* b_l0f   = (const float*)d_in[3];
    const float* Wih_l0b = (const float*)d_in[4];
    const float* Whh_l0b = (const float*)d_in[5];
    const float* b_l0b   = (const float*)d_in[6];
    const float* Wih_l1f = (const float*)d_in[7];
    const float* Whh_l1f = (const float*)d_in[8];
    const float* b_l1f   = (const float*)d_in[9];
    const float* Wih_l1b = (const float*)d_in[10];
    const float* Whh_l1b = (const float*)d_in[11];
    const float* b_l1b   = (const float*)d_in[12];
    const float* fcw     = (const float*)d_in[13];
    const float* fcb     = (const float*)d_in[14];

    const size_t o_xpad   = 0;
    const size_t o_out0   = o_xpad + (size_t)BB * TT * 32 * 2;
    const size_t o_pooled = o_out0 + (size_t)BB * TT * 128 * 2;

    _Float16* xpad   = (_Float16*)((char*)d_ws + o_xpad);
    _Float16* out0   = (_Float16*)((char*)d_ws + o_out0);
    float*    pooled = (float*)((char*)d_ws + o_pooled);

    xpad_prep<<<(BB * TT * 4) / 256, 256, 0, stream>>>(x, xpad);
    lstm_l0<<<(BB / 16) * 2, 256, 0, stream>>>(xpad, Wih_l0f, Whh_l0f, b_l0f,
                                               Wih_l0b, Whh_l0b, b_l0b, out0);
    lstm_l1<<<(BB / 16) * 2, 256, 0, stream>>>(out0, Wih_l1f, Whh_l1f, b_l1f,
                                               Wih_l1b, Whh_l1b, b_l1b, pooled);
    fc_head<<<BB, 64, 0, stream>>>(pooled, fcw, fcb, (float*)d_out);
}

// Round 6
// 833.571 us; speedup vs baseline: 1.0575x; 1.0575x over previous
//
#include <hip/hip_runtime.h>

#define H  64
#define TT 512
#define BB 512

typedef _Float16 half8 __attribute__((ext_vector_type(8)));
typedef float    f32x4 __attribute__((ext_vector_type(4)));

__device__ __forceinline__ float frcp(float x) { return __builtin_amdgcn_rcpf(x); }
__device__ __forceinline__ float sigm(float x) { return frcp(1.f + __expf(-x)); }
__device__ __forceinline__ float tanh_fast(float x) { return 1.f - 2.f * frcp(__expf(2.f * x) + 1.f); }

// ---------------------------------------------------------------------------
// xpad: [B*T][32] fp16, cols 0..3 = x (fp32->fp16), cols 4..31 = 0.
// ---------------------------------------------------------------------------
__global__ __launch_bounds__(256) void xpad_prep(const float* __restrict__ x,
                                                 _Float16* __restrict__ xpad) {
    int gid = blockIdx.x * 256 + threadIdx.x;
    int row = gid >> 2, q = gid & 3;
    half8 v = {0,0,0,0,0,0,0,0};
    if (q == 0) {
        float4 xv = ((const float4*)x)[row];
        v[0] = (_Float16)xv.x; v[1] = (_Float16)xv.y;
        v[2] = (_Float16)xv.z; v[3] = (_Float16)xv.w;
    }
    *(half8*)(xpad + (size_t)row * 32 + q * 8) = v;
}

// ---------------------------------------------------------------------------
// MFMA LSTM layer 0. Block = 256 thr = 4 waves, 16 chains (same dir).
// Critical path per step: ds_read h -> 2 dependent h-MFMAs -> activations.
// x-part of step s+1 computed into xacc during step s (bias folded in).
// Global ops (x prefetch, out0 store of previous h) issued at top of step so
// the __syncthreads vmcnt(0) drain costs ~nothing.
// ---------------------------------------------------------------------------
__global__ __launch_bounds__(256) void lstm_l0(
    const _Float16* __restrict__ xpad,
    const float* __restrict__ WihF, const float* __restrict__ WhhF, const float* __restrict__ bF,
    const float* __restrict__ WihB, const float* __restrict__ WhhB, const float* __restrict__ bB,
    _Float16* __restrict__ out0)
{
    const int dir = blockIdx.x & 1;
    const int b0  = (blockIdx.x >> 1) * 16;
    const int tid = threadIdx.x;
    const int w = tid >> 6, l = tid & 63, m = l & 15, q = l >> 4;

    const float* Wih = dir ? WihB : WihF;
    const float* Whh = dir ? WhhB : WhhF;
    const float* bia = dir ? bB   : bF;

    half8 Bh[4][2], Bx[4];
    float bv[4];
#pragma unroll
    for (int g = 0; g < 4; ++g) {
        const int n = g * 64 + w * 16 + m;
        bv[g] = bia[n];
#pragma unroll
        for (int s = 0; s < 2; ++s) {
            const float* src = Whh + n * 64 + s * 32 + q * 8;
            half8 tmp;
#pragma unroll
            for (int j = 0; j < 8; ++j) tmp[j] = (_Float16)src[j];
            Bh[g][s] = tmp;
        }
        half8 tx;
#pragma unroll
        for (int j = 0; j < 8; ++j) {
            int k = q * 8 + j;
            tx[j] = (k < 4) ? (_Float16)Wih[n * 4 + k] : (_Float16)0.f;
        }
        Bx[g] = tx;
    }

    __shared__ _Float16 hbuf[2][1024];
    ((unsigned long long*)hbuf)[tid] = 0ULL;
    __syncthreads();

    float c[4] = {0.f, 0.f, 0.f, 0.f};
    float hprev[4];
    const int dt = dir ? -1 : 1;
    int t = dir ? TT - 1 : 0;
    int tprev = t;
    const _Float16* xrow = xpad + (size_t)(b0 + m) * TT * 32 + q * 8;
    const int swz = (m & 7) * 16;

    // Prologue: xacc for step 0; prefetch x for step 1.
    half8 ax0 = *(const half8*)(xrow + t * 32);
    f32x4 xacc[4], xaccn[4];
#pragma unroll
    for (int g = 0; g < 4; ++g) {
        f32x4 a = {bv[g], bv[g], bv[g], bv[g]};
        xacc[g] = __builtin_amdgcn_mfma_f32_16x16x32_f16(ax0, Bx[g], a, 0, 0, 0);
    }
    int t1 = t + dt; if (t1 < 0 || t1 >= TT) t1 = t;
    half8 axn = *(const half8*)(xrow + t1 * 32);
    int p = 0;

    for (int s = 0; s < TT; ++s) {
        // top-of-step global ops: full step in flight before next vmcnt drain
        int t2 = t + 2 * dt; if (t2 < 0 || t2 >= TT) t2 = t;
        half8 axn2 = *(const half8*)(xrow + t2 * 32);
        if (s) {
#pragma unroll
            for (int i = 0; i < 4; ++i)
                out0[((size_t)(b0 + q * 4 + i) * TT + tprev) * 128 + dir * 64 + w * 16 + m]
                    = (_Float16)hprev[i];
        }

        const char* hb = (const char*)hbuf[p];
        half8 ah0 = *(const half8*)(hb + m * 128 + ((     q * 16 + swz) & 127));
        half8 ah1 = *(const half8*)(hb + m * 128 + ((64 + q * 16 + swz) & 127));

        f32x4 acc[4];
#pragma unroll
        for (int g = 0; g < 4; ++g) {
            f32x4 a = __builtin_amdgcn_mfma_f32_16x16x32_f16(ah0, Bh[g][0], xacc[g], 0, 0, 0);
            acc[g]  = __builtin_amdgcn_mfma_f32_16x16x32_f16(ah1, Bh[g][1], a, 0, 0, 0);
        }
        // independent: x-part for step s+1
#pragma unroll
        for (int g = 0; g < 4; ++g) {
            f32x4 a = {bv[g], bv[g], bv[g], bv[g]};
            xaccn[g] = __builtin_amdgcn_mfma_f32_16x16x32_f16(axn, Bx[g], a, 0, 0, 0);
        }

        char* hbn = (char*)hbuf[p ^ 1];
#pragma unroll
        for (int i = 0; i < 4; ++i) {
            float e_i = sigm(acc[0][i]), e_f = sigm(acc[1][i]);
            float e_g = tanh_fast(acc[2][i]), e_o = sigm(acc[3][i]);
            c[i] = e_f * c[i] + e_i * e_g;
            float hh = e_o * tanh_fast(c[i]);
            hprev[i] = hh;
            const int ch = q * 4 + i;
            *(_Float16*)(hbn + ch * 128 + (((w * 16 + m) * 2 + (ch & 7) * 16) & 127)) = (_Float16)hh;
        }
        __syncthreads();
#pragma unroll
        for (int g = 0; g < 4; ++g) xacc[g] = xaccn[g];
        axn = axn2;
        p ^= 1; tprev = t; t += dt;
    }
#pragma unroll
    for (int i = 0; i < 4; ++i)
        out0[((size_t)(b0 + q * 4 + i) * TT + tprev) * 128 + dir * 64 + w * 16 + m]
            = (_Float16)hprev[i];
}

// ---------------------------------------------------------------------------
// MFMA LSTM layer 1: x-part = 4 MFMAs (K=128) pipelined one step ahead;
// critical path = 2 h-MFMAs + activations. Accumulates hsum for mean-pool.
// ---------------------------------------------------------------------------
__global__ __launch_bounds__(256) void lstm_l1(
    const _Float16* __restrict__ out0,
    const float* __restrict__ WihF, const float* __restrict__ WhhF, const float* __restrict__ bF,
    const float* __restrict__ WihB, const float* __restrict__ WhhB, const float* __restrict__ bB,
    float* __restrict__ pooled)
{
    const int dir = blockIdx.x & 1;
    const int b0  = (blockIdx.x >> 1) * 16;
    const int tid = threadIdx.x;
    const int w = tid >> 6, l = tid & 63, m = l & 15, q = l >> 4;

    const float* Wih = dir ? WihB : WihF;
    const float* Whh = dir ? WhhB : WhhF;
    const float* bia = dir ? bB   : bF;

    half8 Bf[4][6];   // [g][0..1]=Whh K-slices, [g][2..5]=Wih K-slices
    float bv[4];
#pragma unroll
    for (int g = 0; g < 4; ++g) {
        const int n = g * 64 + w * 16 + m;
        bv[g] = bia[n];
#pragma unroll
        for (int s = 0; s < 6; ++s) {
            const float* src = (s < 2) ? (Whh + n * 64 + s * 32 + q * 8)
                                       : (Wih + n * 128 + (s - 2) * 32 + q * 8);
            half8 tmp;
#pragma unroll
            for (int j = 0; j < 8; ++j) tmp[j] = (_Float16)src[j];
            Bf[g][s] = tmp;
        }
    }

    __shared__ _Float16 hbuf[2][1024];
    ((unsigned long long*)hbuf)[tid] = 0ULL;
    __syncthreads();

    float c[4]  = {0.f, 0.f, 0.f, 0.f};
    float hs[4] = {0.f, 0.f, 0.f, 0.f};
    const int dt = dir ? -1 : 1;
    int t = dir ? TT - 1 : 0;
    const _Float16* xrow = out0 + (size_t)(b0 + m) * TT * 128 + q * 8;
    const int swz = (m & 7) * 16;

    // Prologue: xacc for step 0; prefetch x for step 1.
    half8 ax[4];
#pragma unroll
    for (int s4 = 0; s4 < 4; ++s4) ax[s4] = *(const half8*)(xrow + t * 128 + s4 * 32);
    f32x4 xacc[4], xaccn[4];
#pragma unroll
    for (int g = 0; g < 4; ++g) {
        f32x4 a = {bv[g], bv[g], bv[g], bv[g]};
        a = __builtin_amdgcn_mfma_f32_16x16x32_f16(ax[0], Bf[g][2], a, 0, 0, 0);
        a = __builtin_amdgcn_mfma_f32_16x16x32_f16(ax[1], Bf[g][3], a, 0, 0, 0);
        a = __builtin_amdgcn_mfma_f32_16x16x32_f16(ax[2], Bf[g][4], a, 0, 0, 0);
        xacc[g] = __builtin_amdgcn_mfma_f32_16x16x32_f16(ax[3], Bf[g][5], a, 0, 0, 0);
    }
    int t1 = t + dt; if (t1 < 0 || t1 >= TT) t1 = t;
    half8 axn[4];
#pragma unroll
    for (int s4 = 0; s4 < 4; ++s4) axn[s4] = *(const half8*)(xrow + t1 * 128 + s4 * 32);
    int p = 0;

    for (int s = 0; s < TT; ++s) {
        int t2 = t + 2 * dt; if (t2 < 0 || t2 >= TT) t2 = t;
        half8 axn2[4];
#pragma unroll
        for (int s4 = 0; s4 < 4; ++s4) axn2[s4] = *(const half8*)(xrow + t2 * 128 + s4 * 32);

        const char* hb = (const char*)hbuf[p];
        half8 ah0 = *(const half8*)(hb + m * 128 + ((     q * 16 + swz) & 127));
        half8 ah1 = *(const half8*)(hb + m * 128 + ((64 + q * 16 + swz) & 127));

        f32x4 acc[4];
#pragma unroll
        for (int g = 0; g < 4; ++g) {
            f32x4 a = __builtin_amdgcn_mfma_f32_16x16x32_f16(ah0, Bf[g][0], xacc[g], 0, 0, 0);
            acc[g]  = __builtin_amdgcn_mfma_f32_16x16x32_f16(ah1, Bf[g][1], a, 0, 0, 0);
        }
        // independent: x-part for step s+1
#pragma unroll
        for (int g = 0; g < 4; ++g) {
            f32x4 a = {bv[g], bv[g], bv[g], bv[g]};
            a = __builtin_amdgcn_mfma_f32_16x16x32_f16(axn[0], Bf[g][2], a, 0, 0, 0);
            a = __builtin_amdgcn_mfma_f32_16x16x32_f16(axn[1], Bf[g][3], a, 0, 0, 0);
            a = __builtin_amdgcn_mfma_f32_16x16x32_f16(axn[2], Bf[g][4], a, 0, 0, 0);
            xaccn[g] = __builtin_amdgcn_mfma_f32_16x16x32_f16(axn[3], Bf[g][5], a, 0, 0, 0);
        }

        char* hbn = (char*)hbuf[p ^ 1];
#pragma unroll
        for (int i = 0; i < 4; ++i) {
            float e_i = sigm(acc[0][i]), e_f = sigm(acc[1][i]);
            float e_g = tanh_fast(acc[2][i]), e_o = sigm(acc[3][i]);
            c[i] = e_f * c[i] + e_i * e_g;
            float hh = e_o * tanh_fast(c[i]);
            hs[i] += hh;
            const int ch = q * 4 + i;
            *(_Float16*)(hbn + ch * 128 + (((w * 16 + m) * 2 + (ch & 7) * 16) & 127)) = (_Float16)hh;
        }
        __syncthreads();
#pragma unroll
        for (int g = 0; g < 4; ++g) xacc[g] = xaccn[g];
#pragma unroll
        for (int s4 = 0; s4 < 4; ++s4) axn[s4] = axn2[s4];
        p ^= 1; t += dt;
    }

#pragma unroll
    for (int i = 0; i < 4; ++i)
        pooled[(size_t)(b0 + q * 4 + i) * 128 + dir * 64 + w * 16 + m] = hs[i];
}

// ---------------------------------------------------------------------------
// Head: out[b] = dot(pooled[b], fcw) / T + fcb
// ---------------------------------------------------------------------------
__global__ __launch_bounds__(64) void fc_head(
    const float* __restrict__ pooled,
    const float* __restrict__ fcw, const float* __restrict__ fcb,
    float* __restrict__ out)
{
    const int b = blockIdx.x;
    const int l = threadIdx.x;
    float v = pooled[b * 128 + l] * fcw[l] + pooled[b * 128 + 64 + l] * fcw[64 + l];
#pragma unroll
    for (int o = 32; o > 0; o >>= 1) v += __shfl_down(v, o);
    if (l == 0) out[b] = v * (1.f / (float)TT) + fcb[0];
}

extern "C" void kernel_launch(void* const* d_in, const int* in_sizes, int n_in,
                              void* d_out, int out_size, void* d_ws, size_t ws_size,
                              hipStream_t stream) {
    const float* x       = (const float*)d_in[0];
    const float* Wih_l0f = (const float*)d_in[1];
    const float* Whh_l0f = (const float*)d_in[2];
    const float* b_l0f   = (const float*)d_in[3];
    const float* Wih_l0b = (const float*)d_in[4];
    const float* Whh_l0b = (const float*)d_in[5];
    const float* b_l0b   = (const float*)d_in[6];
    const float* Wih_l1f = (const float*)d_in[7];
    const float* Whh_l1f = (const float*)d_in[8];
    const float* b_l1f   = (const float*)d_in[9];
    const float* Wih_l1b = (const float*)d_in[10];
    const float* Whh_l1b = (const float*)d_in[11];
    const float* b_l1b   = (const float*)d_in[12];
    const float* fcw     = (const float*)d_in[13];
    const float* fcb     = (const float*)d_in[14];

    const size_t o_xpad   = 0;
    const size_t o_out0   = o_xpad + (size_t)BB * TT * 32 * 2;
    const size_t o_pooled = o_out0 + (size_t)BB * TT * 128 * 2;

    _Float16* xpad   = (_Float16*)((char*)d_ws + o_xpad);
    _Float16* out0   = (_Float16*)((char*)d_ws + o_out0);
    float*    pooled = (float*)((char*)d_ws + o_pooled);

    xpad_prep<<<(BB * TT * 4) / 256, 256, 0, stream>>>(x, xpad);
    lstm_l0<<<(BB / 16) * 2, 256, 0, stream>>>(xpad, Wih_l0f, Whh_l0f, b_l0f,
                                               Wih_l0b, Whh_l0b, b_l0b, out0);
    lstm_l1<<<(BB / 16) * 2, 256, 0, stream>>>(out0, Wih_l1f, Whh_l1f, b_l1f,
                                               Wih_l1b, Whh_l1b, b_l1b, pooled);
    fc_head<<<BB, 64, 0, stream>>>(pooled, fcw, fcb, (float*)d_out);
}